// Round 8
// baseline (678.910 us; speedup 1.0000x reference)
//
#include <hip/hip_runtime.h>
#include <math.h>

#define NUM_ENT 100000
#define NUM_EDGES 200000
#define DIM 768
#define BM 64
#define KSTEPS 24
#define NC 16
#define DCH 48

typedef float f32x4 __attribute__((ext_vector_type(4)));
typedef __bf16 bf16x8 __attribute__((ext_vector_type(8)));

// ---- ws layout (float indices) ----
#define WS_Y1    0        // 3*768
#define WS_CQ    2304     // 3*768
#define WS_HA    4704     // 3 hop_attn
#define WS_HOP1  4736     // 256
#define WS_CTX   4992     // 3*768
#define WS_B     7424     // bf16 frag-ordered: 24 chunks * 48 frags * 1KB
#define WS_DPROB 302336   // 3*200000 (also transient home of P1/P2 partials)
#define WS_P1    302336   // 48*768
#define WS_P1H   339200   // 16*256
#define WS_P2    343296   // 48*768
#define WS_E     902336   // 4*100000 (slot 0 unused; e1..e3 raw sums)

__device__ __forceinline__ unsigned short f2bf(float f) {
    unsigned int x = __builtin_bit_cast(unsigned int, f);
    x = x + 0x7fffu + ((x >> 16) & 1u);   // RTNE
    return (unsigned short)(x >> 16);
}

// A&S 7.1.26 erf approx, |eps| <= 1.5e-7
__device__ __forceinline__ float gelu_f(float x) {
    float z = 0.70710678118654752f * x;
    float s = fabsf(z);
    float t = 1.f / (1.f + 0.3275911f * s);
    float p = t * (0.254829592f + t * (-0.284496736f + t * (1.421413741f +
              t * (-1.453152027f + t * 1.061405429f))));
    float e = __expf(-s * s);
    float erfa = copysignf(1.f - p * e, z);
    return 0.5f * x * (1.f + erfa);
}

// K1a: d-split partials for step layer-1 (48 blocks) and hop layer-1 (16 blocks)
__global__ void k1a(const float* __restrict__ q, const float* __restrict__ sw1,
                    const float* __restrict__ hw1, float* __restrict__ ws) {
    int b = blockIdx.x, tid = threadIdx.x;
    if (b < 48) {
        int t = b >> 4, c = b & 15;
        const float* w = sw1 + (size_t)t * DIM * DIM + (size_t)c * DCH * DIM;
        float a0 = 0.f, a1 = 0.f, a2 = 0.f;
        for (int d = 0; d < DCH; ++d) {
            float qv = q[c * DCH + d];
            const float* wr = w + (size_t)d * DIM;
            a0 += qv * wr[tid]; a1 += qv * wr[tid + 256]; a2 += qv * wr[tid + 512];
        }
        float* p = ws + WS_P1 + (size_t)b * DIM;
        p[tid] = a0; p[tid + 256] = a1; p[tid + 512] = a2;
    } else {
        int c = b - 48;
        const float* w = hw1 + (size_t)c * DCH * 256;
        float a0 = 0.f;
        for (int d = 0; d < DCH; ++d) a0 += q[c * DCH + d] * w[(size_t)d * 256 + tid];
        ws[WS_P1H + c * 256 + tid] = a0;
    }
}

// K1b: reduce partials + bias + gelu -> y1, hop1
__global__ void k1b(const float* __restrict__ sb1, const float* __restrict__ hb1,
                    float* __restrict__ ws) {
    int o = blockIdx.x * 256 + threadIdx.x;
    if (o < 2304) {
        int t = o / DIM, j = o % DIM;
        float s = sb1[o];
        for (int c = 0; c < NC; ++c) s += ws[WS_P1 + (size_t)(t * 16 + c) * DIM + j];
        ws[WS_Y1 + o] = gelu_f(s);
    } else if (o < 2560) {
        int j = o - 2304;
        float s = hb1[j];
        for (int c = 0; c < NC; ++c) s += ws[WS_P1H + c * 256 + j];
        ws[WS_HOP1 + j] = gelu_f(s);
    }
}

// K2a: d-split partials for step layer-2
__global__ void k2a(const float* __restrict__ sw2, float* __restrict__ ws) {
    int b = blockIdx.x, tid = threadIdx.x;
    int t = b >> 4, c = b & 15;
    const float* w = sw2 + (size_t)t * DIM * DIM + (size_t)c * DCH * DIM;
    const float* y = ws + WS_Y1 + t * DIM + c * DCH;
    float a0 = 0.f, a1 = 0.f, a2 = 0.f;
    for (int d = 0; d < DCH; ++d) {
        float yv = y[d];
        const float* wr = w + (size_t)d * DIM;
        a0 += yv * wr[tid]; a1 += yv * wr[tid + 256]; a2 += yv * wr[tid + 512];
    }
    float* p = ws + WS_P2 + (size_t)b * DIM;
    p[tid] = a0; p[tid + 256] = a1; p[tid + 512] = a2;
}

// K2b: reduce -> cq
__global__ void k2b(const float* __restrict__ sb2, float* __restrict__ ws) {
    int o = blockIdx.x * 256 + threadIdx.x;   // 0..2303
    int t = o / DIM, j = o % DIM;
    float s = sb2[o];
    for (int c = 0; c < NC; ++c) s += ws[WS_P2 + (size_t)(t * 16 + c) * DIM + j];
    ws[WS_CQ + o] = s;
}

// K345 (single block, 1024 thr): q_logits -> softmax -> ctx; hop_attn
__global__ void k345(const float* __restrict__ qwh, const float* __restrict__ hw2,
                     const float* __restrict__ hb2, float* __restrict__ ws) {
    __shared__ float qlog[96];
    int tid = threadIdx.x;
    int w = tid >> 6, lane = tid & 63;
    for (int s = 0; s < 6; ++s) {
        int p = w * 6 + s;
        int t = p >> 5, l = p & 31;
        const float* c = ws + WS_CQ + t * DIM;
        const float* qw = qwh + l * DIM;
        float acc = 0.f;
        for (int i = lane; i < DIM; i += 64) acc += c[i] * qw[i];
        for (int m = 32; m; m >>= 1) acc += __shfl_xor(acc, m);
        if (lane == 0) qlog[p] = acc;
    }
    __syncthreads();
    if (tid < 64) {
        for (int t = 0; t < 3; ++t) {
            float v = (lane < 32) ? qlog[t * 32 + lane] : -1e30f;
            float mx = v;
            for (int m = 1; m < 32; m <<= 1) mx = fmaxf(mx, __shfl_xor(mx, m, 32));
            float e = (lane < 32) ? __expf(v - mx) : 0.f;
            float s = e;
            for (int m = 1; m < 32; m <<= 1) s += __shfl_xor(s, m, 32);
            if (lane < 32) qlog[t * 32 + lane] = e / s;
        }
        float lg = 0.f;
        if (lane < 3) {
            for (int s = 0; s < 256; ++s) lg += ws[WS_HOP1 + s] * hw2[s * 3 + lane];
            lg += hb2[lane];
        }
        float l0 = __shfl(lg, 0), l1 = __shfl(lg, 1), l2 = __shfl(lg, 2);
        if (lane == 0) {
            float mx = fmaxf(l0, fmaxf(l1, l2));
            float e0 = __expf(l0 - mx), e1 = __expf(l1 - mx), e2 = __expf(l2 - mx);
            float s = e0 + e1 + e2;
            ws[WS_HA + 0] = e0 / s; ws[WS_HA + 1] = e1 / s; ws[WS_HA + 2] = e2 / s;
        }
    }
    __syncthreads();
    for (int o = tid; o < 2304; o += 1024) {
        int t = o / DIM, d = o % DIM;
        float acc = ws[WS_CQ + o];
        const float* qd = qlog + t * 32;
        for (int l = 0; l < 32; ++l) acc += qd[l] * qwh[l * DIM + d];
        ws[WS_CTX + o] = acc;
    }
}

// K6: B bf16, K-chunk-major frag order: chunk ks (0..23) holds 48 frags (t*16+cf)
__global__ void k6_bmat(const float* __restrict__ rw1, float* __restrict__ ws) {
    int g = blockIdx.x * 256 + threadIdx.x;   // 0..73727
    int lane = g & 63, f = g >> 6;            // f 0..1151
    int ks = f / 48, r = f % 48;
    int t = r >> 4, cf = r & 15;
    int k0 = ks * 32 + (lane >> 4) * 8;
    int col = cf * 16 + (lane & 15);
    const float* ctx = ws + WS_CTX + t * DIM;
    union { unsigned short u[8]; bf16x8 v; } pk;
    #pragma unroll
    for (int j = 0; j < 8; ++j) {
        float v = ctx[k0 + j] * rw1[(size_t)(k0 + j) * 256 + col];
        pk.u[j] = f2bf(v);
    }
    *(bf16x8*)((unsigned short*)(ws + WS_B) + (size_t)g * 8) = pk.v;
}

#define MFMA4(A, B0, B1, B2, B3, RF)                                               \
    acc[RF][0] = __builtin_amdgcn_mfma_f32_16x16x32_bf16(A, B0, acc[RF][0], 0,0,0); \
    acc[RF][1] = __builtin_amdgcn_mfma_f32_16x16x32_bf16(A, B1, acc[RF][1], 0,0,0); \
    acc[RF][2] = __builtin_amdgcn_mfma_f32_16x16x32_bf16(A, B2, acc[RF][2], 0,0,0); \
    acc[RF][3] = __builtin_amdgcn_mfma_f32_16x16x32_bf16(A, B3, acc[RF][3], 0,0,0);

// K7: barrier-free K-loop GEMM + fused epilogue (exact r5 461us version)
__global__ __launch_bounds__(768, 3)
void k7_gemm(const float* __restrict__ desc, const float* __restrict__ rb1,
             const float* __restrict__ rw2, const float* __restrict__ rb2,
             float* __restrict__ ws) {
    extern __shared__ char lds[];
    unsigned short* aLds = (unsigned short*)lds;   // 96 frags * 512 ushort
    float* part = (float*)(lds + 98304);           // 12 * 64

    const unsigned short* bmat = (const unsigned short*)(ws + WS_B);
    float* dprob = ws + WS_DPROB;
    int tid = threadIdx.x, blk = blockIdx.x;
    int wid = tid >> 6, lane = tid & 63;
    int t = wid >> 2, cg = wid & 3;
    int fbase = (t << 4) + (cg << 2);

    const unsigned short* bp = bmat + ((size_t)fbase << 9) + lane * 8;
    bf16x8 b0_0 = *(const bf16x8*)(bp);
    bf16x8 b0_1 = *(const bf16x8*)(bp + 512);
    bf16x8 b0_2 = *(const bf16x8*)(bp + 1024);
    bf16x8 b0_3 = *(const bf16x8*)(bp + 1536);
    bp += 48 * 512;

    #pragma unroll
    for (int i = 0; i < 8; ++i) {
        int gf = i * 768 + tid;
        int l = gf & 63, f = gf >> 6;
        int ks = f >> 2, rf = f & 3;
        int row = rf * 16 + (l & 15);
        int kb = ks * 32 + (l >> 4) * 8;
        const float* src = desc + (size_t)(blk * BM + row) * DIM + kb;
        float4 v0 = *(const float4*)src;
        float4 v1 = *(const float4*)(src + 4);
        bf16x8 pk;
        pk[0] = (__bf16)v0.x; pk[1] = (__bf16)v0.y; pk[2] = (__bf16)v0.z; pk[3] = (__bf16)v0.w;
        pk[4] = (__bf16)v1.x; pk[5] = (__bf16)v1.y; pk[6] = (__bf16)v1.z; pk[7] = (__bf16)v1.w;
        *(bf16x8*)(aLds + (size_t)f * 512 + l * 8) = pk;
    }
    __syncthreads();

    f32x4 acc[4][4];
    #pragma unroll
    for (int rf = 0; rf < 4; ++rf)
        #pragma unroll
        for (int i = 0; i < 4; ++i) acc[rf][i] = f32x4{0.f, 0.f, 0.f, 0.f};

    const unsigned short* ab0 = aLds + lane * 8;
    bf16x8 b1_0, b1_1, b1_2, b1_3;

    #pragma unroll 1
    for (int ks = 0; ks < KSTEPS; ks += 2) {
        b1_0 = *(const bf16x8*)(bp);
        b1_1 = *(const bf16x8*)(bp + 512);
        b1_2 = *(const bf16x8*)(bp + 1024);
        b1_3 = *(const bf16x8*)(bp + 1536);
        bp += 48 * 512;
        {
            const unsigned short* ab = ab0 + (size_t)ks * 2048;
            bf16x8 a;
            a = *(const bf16x8*)(ab);          MFMA4(a, b0_0, b0_1, b0_2, b0_3, 0)
            a = *(const bf16x8*)(ab + 512);    MFMA4(a, b0_0, b0_1, b0_2, b0_3, 1)
            a = *(const bf16x8*)(ab + 1024);   MFMA4(a, b0_0, b0_1, b0_2, b0_3, 2)
            a = *(const bf16x8*)(ab + 1536);   MFMA4(a, b0_0, b0_1, b0_2, b0_3, 3)
        }
        if (ks + 2 < KSTEPS) {
            b0_0 = *(const bf16x8*)(bp);
            b0_1 = *(const bf16x8*)(bp + 512);
            b0_2 = *(const bf16x8*)(bp + 1024);
            b0_3 = *(const bf16x8*)(bp + 1536);
            bp += 48 * 512;
        }
        {
            const unsigned short* ab = ab0 + (size_t)ks * 2048 + 2048;
            bf16x8 a;
            a = *(const bf16x8*)(ab);          MFMA4(a, b1_0, b1_1, b1_2, b1_3, 0)
            a = *(const bf16x8*)(ab + 512);    MFMA4(a, b1_0, b1_1, b1_2, b1_3, 1)
            a = *(const bf16x8*)(ab + 1024);   MFMA4(a, b1_0, b1_1, b1_2, b1_3, 2)
            a = *(const bf16x8*)(ab + 1536);   MFMA4(a, b1_0, b1_1, b1_2, b1_3, 3)
        }
    }

    int col16 = lane & 15, quart = lane >> 4;
    float b1v[4], w2v[4];
    #pragma unroll
    for (int i = 0; i < 4; ++i) {
        int c = cg * 64 + i * 16 + col16;
        b1v[i] = rb1[c]; w2v[i] = rw2[c];
    }
    #pragma unroll
    for (int rf = 0; rf < 4; ++rf) {
        #pragma unroll
        for (int r = 0; r < 4; ++r) {
            float s = 0.f;
            #pragma unroll
            for (int i = 0; i < 4; ++i)
                s += gelu_f(acc[rf][i][r] + b1v[i]) * w2v[i];
            #pragma unroll
            for (int m = 1; m < 16; m <<= 1) s += __shfl_xor(s, m);
            if (col16 == 0) part[wid * 64 + rf * 16 + quart * 4 + r] = s;
        }
    }
    __syncthreads();
    if (tid < 192) {
        int tt = tid >> 6, row = tid & 63;
        float v = part[(tt * 4 + 0) * 64 + row] + part[(tt * 4 + 1) * 64 + row]
                + part[(tt * 4 + 2) * 64 + row] + part[(tt * 4 + 3) * 64 + row] + rb2[0];
        float p = 1.f / (1.f + __expf(-v));
        dprob[(size_t)tt * NUM_EDGES + blk * BM + row] = p;
    }
}

// ---- DIAGNOSTIC PROBES: k7 K-loop component ablation (within-probe A/B) ----
// MODE bit0: real B global loads in K-loop (else B frozen in regs from prologue)
// MODE bit1: real A ds_reads in K-loop (else A frozen in regs)
// V1=<3> clone control, V2=<2> no-B, V3=<1> no-A-LDS, V4=<0> MFMA-only floor.
// Output kept live via never-true conditional store (rule #17).
template<int MODE>
__global__ __launch_bounds__(768, 3)
void k7probe(const float* __restrict__ desc, float* __restrict__ ws) {
    extern __shared__ char lds[];
    unsigned short* aLds = (unsigned short*)lds;
    const unsigned short* bmat = (const unsigned short*)(ws + WS_B);
    int tid = threadIdx.x, blk = blockIdx.x;
    int wid = tid >> 6, lane = tid & 63;
    int t = wid >> 2, cg = wid & 3;
    int fbase = (t << 4) + (cg << 2);

    const unsigned short* bp = bmat + ((size_t)fbase << 9) + lane * 8;
    bf16x8 b0_0 = *(const bf16x8*)(bp);
    bf16x8 b0_1 = *(const bf16x8*)(bp + 512);
    bf16x8 b0_2 = *(const bf16x8*)(bp + 1024);
    bf16x8 b0_3 = *(const bf16x8*)(bp + 1536);
    bp += 48 * 512;

    #pragma unroll
    for (int i = 0; i < 8; ++i) {
        int gf = i * 768 + tid;
        int l = gf & 63, f = gf >> 6;
        int ks = f >> 2, rf = f & 3;
        int row = rf * 16 + (l & 15);
        int kb = ks * 32 + (l >> 4) * 8;
        const float* src = desc + (size_t)(blk * BM + row) * DIM + kb;
        float4 v0 = *(const float4*)src;
        float4 v1 = *(const float4*)(src + 4);
        bf16x8 pk;
        pk[0] = (__bf16)v0.x; pk[1] = (__bf16)v0.y; pk[2] = (__bf16)v0.z; pk[3] = (__bf16)v0.w;
        pk[4] = (__bf16)v1.x; pk[5] = (__bf16)v1.y; pk[6] = (__bf16)v1.z; pk[7] = (__bf16)v1.w;
        *(bf16x8*)(aLds + (size_t)f * 512 + l * 8) = pk;
    }
    __syncthreads();

    f32x4 acc[4][4];
    #pragma unroll
    for (int rf = 0; rf < 4; ++rf)
        #pragma unroll
        for (int i = 0; i < 4; ++i) acc[rf][i] = f32x4{0.f, 0.f, 0.f, 0.f};

    const unsigned short* ab0 = aLds + lane * 8;
    bf16x8 ac0 = *(const bf16x8*)(ab0);
    bf16x8 ac1 = *(const bf16x8*)(ab0 + 512);
    bf16x8 ac2 = *(const bf16x8*)(ab0 + 1024);
    bf16x8 ac3 = *(const bf16x8*)(ab0 + 1536);
    bf16x8 b1_0, b1_1, b1_2, b1_3;

    #pragma unroll 1
    for (int ks = 0; ks < KSTEPS; ks += 2) {
        if constexpr (MODE & 1) {
            b1_0 = *(const bf16x8*)(bp);
            b1_1 = *(const bf16x8*)(bp + 512);
            b1_2 = *(const bf16x8*)(bp + 1024);
            b1_3 = *(const bf16x8*)(bp + 1536);
            bp += 48 * 512;
        }
        {
            bf16x8 A0, A1, A2, A3;
            if constexpr (MODE & 2) {
                const unsigned short* ab = ab0 + (size_t)ks * 2048;
                A0 = *(const bf16x8*)(ab);
                A1 = *(const bf16x8*)(ab + 512);
                A2 = *(const bf16x8*)(ab + 1024);
                A3 = *(const bf16x8*)(ab + 1536);
            } else { A0 = ac0; A1 = ac1; A2 = ac2; A3 = ac3; }
            bf16x8 a;
            a = A0; MFMA4(a, b0_0, b0_1, b0_2, b0_3, 0)
            a = A1; MFMA4(a, b0_0, b0_1, b0_2, b0_3, 1)
            a = A2; MFMA4(a, b0_0, b0_1, b0_2, b0_3, 2)
            a = A3; MFMA4(a, b0_0, b0_1, b0_2, b0_3, 3)
        }
        if constexpr (MODE & 1) {
            if (ks + 2 < KSTEPS) {
                b0_0 = *(const bf16x8*)(bp);
                b0_1 = *(const bf16x8*)(bp + 512);
                b0_2 = *(const bf16x8*)(bp + 1024);
                b0_3 = *(const bf16x8*)(bp + 1536);
                bp += 48 * 512;
            }
        }
        {
            bf16x8 A0, A1, A2, A3;
            if constexpr (MODE & 2) {
                const unsigned short* ab = ab0 + (size_t)ks * 2048 + 2048;
                A0 = *(const bf16x8*)(ab);
                A1 = *(const bf16x8*)(ab + 512);
                A2 = *(const bf16x8*)(ab + 1024);
                A3 = *(const bf16x8*)(ab + 1536);
            } else { A0 = ac0; A1 = ac1; A2 = ac2; A3 = ac3; }
            bf16x8 B0, B1, B2, B3;
            if constexpr (MODE & 1) { B0 = b1_0; B1 = b1_1; B2 = b1_2; B3 = b1_3; }
            else { B0 = b0_0; B1 = b0_1; B2 = b0_2; B3 = b0_3; }
            bf16x8 a;
            a = A0; MFMA4(a, B0, B1, B2, B3, 0)
            a = A1; MFMA4(a, B0, B1, B2, B3, 1)
            a = A2; MFMA4(a, B0, B1, B2, B3, 2)
            a = A3; MFMA4(a, B0, B1, B2, B3, 3)
        }
    }

    float s = 0.f;
    #pragma unroll
    for (int rf = 0; rf < 4; ++rf)
        #pragma unroll
        for (int i = 0; i < 4; ++i)
            #pragma unroll
            for (int r = 0; r < 4; ++r) s += acc[rf][i][r];
    if (s > 1e30f) ws[WS_Y1] = s;   // never true for these inputs; keeps acc live
}

// Kzero: zero raw accumulators e1..e3
__global__ void kzero(float* __restrict__ ws) {
    int i = blockIdx.x * 256 + threadIdx.x;
    if (i < 3 * NUM_ENT) ws[WS_E + NUM_ENT + i] = 0.f;
}

// K9: scatter step t: e_{t+1}[obj] += norm(e_t)[sub] * dprob[t][e]
__global__ void k9_scatter(const int* __restrict__ kb, const int* __restrict__ topics,
                           float* __restrict__ ws, int t) {
    int e = blockIdx.x * 256 + threadIdx.x;
    if (e >= NUM_EDGES) return;
    int sub = kb[2 * e], obj = kb[2 * e + 1];
    float g;
    if (t == 0) {
        g = (sub == topics[0] || sub == topics[1] || sub == topics[2] || sub == topics[3]) ? 1.f : 0.f;
    } else {
        float v = ws[WS_E + (size_t)t * NUM_ENT + sub];
        g = v / fmaxf(v, 1.f);
    }
    float p = g * ws[WS_DPROB + (size_t)t * NUM_EDGES + e];
    if (p != 0.f) atomicAdd(&ws[WS_E + (size_t)(t + 1) * NUM_ENT + obj], p);
}

// Kout: out[i] = sum_t hop_attn[t] * norm(e_{t+1})[i]
__global__ void kout(const float* __restrict__ ws, float* __restrict__ out) {
    int i = blockIdx.x * 256 + threadIdx.x;
    if (i >= NUM_ENT) return;
    float v1 = ws[WS_E + 1 * NUM_ENT + i]; v1 /= fmaxf(v1, 1.f);
    float v2 = ws[WS_E + 2 * NUM_ENT + i]; v2 /= fmaxf(v2, 1.f);
    float v3 = ws[WS_E + 3 * NUM_ENT + i]; v3 /= fmaxf(v3, 1.f);
    out[i] = ws[WS_HA + 0] * v1 + ws[WS_HA + 1] * v2 + ws[WS_HA + 2] * v3;
}

extern "C" void kernel_launch(void* const* d_in, const int* in_sizes, int n_in,
                              void* d_out, int out_size, void* d_ws, size_t ws_size,
                              hipStream_t stream) {
    const float* q_emb   = (const float*)d_in[0];
    const float* qwh     = (const float*)d_in[1];
    const float* desc    = (const float*)d_in[2];
    const float* sw1     = (const float*)d_in[3];
    const float* sb1     = (const float*)d_in[4];
    const float* sw2     = (const float*)d_in[5];
    const float* sb2     = (const float*)d_in[6];
    const float* rw1     = (const float*)d_in[7];
    const float* rb1     = (const float*)d_in[8];
    const float* rw2     = (const float*)d_in[9];
    const float* rb2     = (const float*)d_in[10];
    const float* hw1     = (const float*)d_in[11];
    const float* hb1     = (const float*)d_in[12];
    const float* hw2     = (const float*)d_in[13];
    const float* hb2     = (const float*)d_in[14];
    const int*   kb      = (const int*)d_in[15];
    const int*   topics  = (const int*)d_in[16];
    float* ws  = (float*)d_ws;
    float* out = (float*)d_out;

    int nblk7 = NUM_EDGES / BM;   // 3125, exact

    kzero<<<(3 * NUM_ENT + 255) / 256, 256, 0, stream>>>(ws);
    k1a<<<64, 256, 0, stream>>>(q_emb, sw1, hw1, ws);
    k1b<<<10, 256, 0, stream>>>(sb1, hb1, ws);
    k2a<<<48, 256, 0, stream>>>(sw2, ws);
    k2b<<<9, 256, 0, stream>>>(sb2, ws);
    k345<<<1, 1024, 0, stream>>>(qwh, hw2, hb2, ws);
    k6_bmat<<<288, 256, 0, stream>>>(rw1, ws);
    k7_gemm<<<nblk7, 768, 101376, stream>>>(desc, rb1, rw2, rb2, ws);

    // diagnostic probes: 768 blocks = exactly 3 full-chip rounds each
    k7probe<3><<<768, 768, 101376, stream>>>(desc, ws);  // V1 clone control
    k7probe<2><<<768, 768, 101376, stream>>>(desc, ws);  // V2: B frozen
    k7probe<1><<<768, 768, 101376, stream>>>(desc, ws);  // V3: A-LDS frozen
    k7probe<0><<<768, 768, 101376, stream>>>(desc, ws);  // V4: MFMA-only floor

    for (int t = 0; t < 3; ++t)
        k9_scatter<<<(NUM_EDGES + 255) / 256, 256, 0, stream>>>(kb, topics, ws, t);
    kout<<<(NUM_ENT + 255) / 256, 256, 0, stream>>>(ws, out);
}

// Round 9
// 467.168 us; speedup vs baseline: 1.4532x; 1.4532x over previous
//
#include <hip/hip_runtime.h>
#include <math.h>

#define NUM_ENT 100000
#define NUM_EDGES 200000
#define DIM 768
#define BM 64
#define KSTEPS 24
#define NC 16
#define DCH 48

typedef float f32x4 __attribute__((ext_vector_type(4)));
typedef __bf16 bf16x8 __attribute__((ext_vector_type(8)));

// ---- ws layout (float indices) ----
#define WS_Y1    0        // 3*768
#define WS_CQ    2304     // 3*768
#define WS_HA    4704     // 3 hop_attn
#define WS_HOP1  4736     // 256
#define WS_CTX   4992     // 3*768
#define WS_B     7424     // bf16 frag-ordered: 24 chunks * 48 frags * 1KB
#define WS_DPROB 302336   // 3*200000 (also transient home of P1/P2 partials)
#define WS_P1    302336   // 48*768
#define WS_P1H   339200   // 16*256
#define WS_P2    343296   // 48*768
#define WS_E     902336   // 4*100000 (slot 0 unused; e1..e3 raw sums)

__device__ __forceinline__ unsigned short f2bf(float f) {
    unsigned int x = __builtin_bit_cast(unsigned int, f);
    x = x + 0x7fffu + ((x >> 16) & 1u);   // RTNE
    return (unsigned short)(x >> 16);
}

// A&S 7.1.26 erf approx, |eps| <= 1.5e-7
__device__ __forceinline__ float gelu_f(float x) {
    float z = 0.70710678118654752f * x;
    float s = fabsf(z);
    float t = 1.f / (1.f + 0.3275911f * s);
    float p = t * (0.254829592f + t * (-0.284496736f + t * (1.421413741f +
              t * (-1.453152027f + t * 1.061405429f))));
    float e = __expf(-s * s);
    float erfa = copysignf(1.f - p * e, z);
    return 0.5f * x * (1.f + erfa);
}

// K1a: d-split partials for step layer-1 (48 blocks) and hop layer-1 (16 blocks)
__global__ void k1a(const float* __restrict__ q, const float* __restrict__ sw1,
                    const float* __restrict__ hw1, float* __restrict__ ws) {
    int b = blockIdx.x, tid = threadIdx.x;
    if (b < 48) {
        int t = b >> 4, c = b & 15;
        const float* w = sw1 + (size_t)t * DIM * DIM + (size_t)c * DCH * DIM;
        float a0 = 0.f, a1 = 0.f, a2 = 0.f;
        for (int d = 0; d < DCH; ++d) {
            float qv = q[c * DCH + d];
            const float* wr = w + (size_t)d * DIM;
            a0 += qv * wr[tid]; a1 += qv * wr[tid + 256]; a2 += qv * wr[tid + 512];
        }
        float* p = ws + WS_P1 + (size_t)b * DIM;
        p[tid] = a0; p[tid + 256] = a1; p[tid + 512] = a2;
    } else {
        int c = b - 48;
        const float* w = hw1 + (size_t)c * DCH * 256;
        float a0 = 0.f;
        for (int d = 0; d < DCH; ++d) a0 += q[c * DCH + d] * w[(size_t)d * 256 + tid];
        ws[WS_P1H + c * 256 + tid] = a0;
    }
}

// K1b: reduce partials + bias + gelu -> y1, hop1
__global__ void k1b(const float* __restrict__ sb1, const float* __restrict__ hb1,
                    float* __restrict__ ws) {
    int o = blockIdx.x * 256 + threadIdx.x;
    if (o < 2304) {
        int t = o / DIM, j = o % DIM;
        float s = sb1[o];
        for (int c = 0; c < NC; ++c) s += ws[WS_P1 + (size_t)(t * 16 + c) * DIM + j];
        ws[WS_Y1 + o] = gelu_f(s);
    } else if (o < 2560) {
        int j = o - 2304;
        float s = hb1[j];
        for (int c = 0; c < NC; ++c) s += ws[WS_P1H + c * 256 + j];
        ws[WS_HOP1 + j] = gelu_f(s);
    }
}

// K2a: d-split partials for step layer-2
__global__ void k2a(const float* __restrict__ sw2, float* __restrict__ ws) {
    int b = blockIdx.x, tid = threadIdx.x;
    int t = b >> 4, c = b & 15;
    const float* w = sw2 + (size_t)t * DIM * DIM + (size_t)c * DCH * DIM;
    const float* y = ws + WS_Y1 + t * DIM + c * DCH;
    float a0 = 0.f, a1 = 0.f, a2 = 0.f;
    for (int d = 0; d < DCH; ++d) {
        float yv = y[d];
        const float* wr = w + (size_t)d * DIM;
        a0 += yv * wr[tid]; a1 += yv * wr[tid + 256]; a2 += yv * wr[tid + 512];
    }
    float* p = ws + WS_P2 + (size_t)b * DIM;
    p[tid] = a0; p[tid + 256] = a1; p[tid + 512] = a2;
}

// K2b: reduce -> cq
__global__ void k2b(const float* __restrict__ sb2, float* __restrict__ ws) {
    int o = blockIdx.x * 256 + threadIdx.x;   // 0..2303
    int t = o / DIM, j = o % DIM;
    float s = sb2[o];
    for (int c = 0; c < NC; ++c) s += ws[WS_P2 + (size_t)(t * 16 + c) * DIM + j];
    ws[WS_CQ + o] = s;
}

// K345 (single block, 1024 thr): q_logits -> softmax -> ctx; hop_attn
__global__ void k345(const float* __restrict__ qwh, const float* __restrict__ hw2,
                     const float* __restrict__ hb2, float* __restrict__ ws) {
    __shared__ float qlog[96];
    int tid = threadIdx.x;
    int w = tid >> 6, lane = tid & 63;
    for (int s = 0; s < 6; ++s) {
        int p = w * 6 + s;
        int t = p >> 5, l = p & 31;
        const float* c = ws + WS_CQ + t * DIM;
        const float* qw = qwh + l * DIM;
        float acc = 0.f;
        for (int i = lane; i < DIM; i += 64) acc += c[i] * qw[i];
        for (int m = 32; m; m >>= 1) acc += __shfl_xor(acc, m);
        if (lane == 0) qlog[p] = acc;
    }
    __syncthreads();
    if (tid < 64) {
        for (int t = 0; t < 3; ++t) {
            float v = (lane < 32) ? qlog[t * 32 + lane] : -1e30f;
            float mx = v;
            for (int m = 1; m < 32; m <<= 1) mx = fmaxf(mx, __shfl_xor(mx, m, 32));
            float e = (lane < 32) ? __expf(v - mx) : 0.f;
            float s = e;
            for (int m = 1; m < 32; m <<= 1) s += __shfl_xor(s, m, 32);
            if (lane < 32) qlog[t * 32 + lane] = e / s;
        }
        float lg = 0.f;
        if (lane < 3) {
            for (int s = 0; s < 256; ++s) lg += ws[WS_HOP1 + s] * hw2[s * 3 + lane];
            lg += hb2[lane];
        }
        float l0 = __shfl(lg, 0), l1 = __shfl(lg, 1), l2 = __shfl(lg, 2);
        if (lane == 0) {
            float mx = fmaxf(l0, fmaxf(l1, l2));
            float e0 = __expf(l0 - mx), e1 = __expf(l1 - mx), e2 = __expf(l2 - mx);
            float s = e0 + e1 + e2;
            ws[WS_HA + 0] = e0 / s; ws[WS_HA + 1] = e1 / s; ws[WS_HA + 2] = e2 / s;
        }
    }
    __syncthreads();
    for (int o = tid; o < 2304; o += 1024) {
        int t = o / DIM, d = o % DIM;
        float acc = ws[WS_CQ + o];
        const float* qd = qlog + t * 32;
        for (int l = 0; l < 32; ++l) acc += qd[l] * qwh[l * DIM + d];
        ws[WS_CTX + o] = acc;
    }
}

// K6: B bf16, K-chunk-major frag order: chunk ks (0..23) holds 48 frags (t*16+cf)
__global__ void k6_bmat(const float* __restrict__ rw1, float* __restrict__ ws) {
    int g = blockIdx.x * 256 + threadIdx.x;   // 0..73727
    int lane = g & 63, f = g >> 6;            // f 0..1151
    int ks = f / 48, r = f % 48;
    int t = r >> 4, cf = r & 15;
    int k0 = ks * 32 + (lane >> 4) * 8;
    int col = cf * 16 + (lane & 15);
    const float* ctx = ws + WS_CTX + t * DIM;
    union { unsigned short u[8]; bf16x8 v; } pk;
    #pragma unroll
    for (int j = 0; j < 8; ++j) {
        float v = ctx[k0 + j] * rw1[(size_t)(k0 + j) * 256 + col];
        pk.u[j] = f2bf(v);
    }
    *(bf16x8*)((unsigned short*)(ws + WS_B) + (size_t)g * 8) = pk.v;
}

#define MFMA4(A, B0, B1, B2, B3, RF)                                               \
    acc[RF][0] = __builtin_amdgcn_mfma_f32_16x16x32_bf16(A, B0, acc[RF][0], 0,0,0); \
    acc[RF][1] = __builtin_amdgcn_mfma_f32_16x16x32_bf16(A, B1, acc[RF][1], 0,0,0); \
    acc[RF][2] = __builtin_amdgcn_mfma_f32_16x16x32_bf16(A, B2, acc[RF][2], 0,0,0); \
    acc[RF][3] = __builtin_amdgcn_mfma_f32_16x16x32_bf16(A, B3, acc[RF][3], 0,0,0);

// K7: barrier-free K-loop GEMM, BOTH operand streams register-pipelined one full
// kstep ahead (r8 ablation: cost was the A<->B load interaction -- each stream
// alone runs at the stage floor; immediate-use loads serialized the loop).
// Two named sets per stream (rule #20), load clusters issued AFTER the consuming
// MFMA block and pinned with sched_barrier(0) so LLVM can't sink them to uses
// (r7 defeat). All waits become counted (lgkmcnt(4)/vmcnt(4)), never draining.
// LDS: A 98304 B @0, part 12x64 f32 @98304 (101376 B total)
__global__ __launch_bounds__(768, 3)
void k7_gemm(const float* __restrict__ desc, const float* __restrict__ rb1,
             const float* __restrict__ rw2, const float* __restrict__ rb2,
             float* __restrict__ ws) {
    extern __shared__ char lds[];
    unsigned short* aLds = (unsigned short*)lds;   // 96 frags * 512 ushort
    float* part = (float*)(lds + 98304);           // 12 * 64

    const unsigned short* bmat = (const unsigned short*)(ws + WS_B);
    float* dprob = ws + WS_DPROB;
    int tid = threadIdx.x, blk = blockIdx.x;
    int wid = tid >> 6, lane = tid & 63;
    int t = wid >> 2, cg = wid & 3;
    int fbase = (t << 4) + (cg << 2);

    const unsigned short* bp0 = bmat + ((size_t)fbase << 9) + lane * 8;

    // ---- prologue: B(0), B(1) in flight during the A stage ----
    bf16x8 b0_0 = *(const bf16x8*)(bp0);
    bf16x8 b0_1 = *(const bf16x8*)(bp0 + 512);
    bf16x8 b0_2 = *(const bf16x8*)(bp0 + 1024);
    bf16x8 b0_3 = *(const bf16x8*)(bp0 + 1536);
    bf16x8 b1_0 = *(const bf16x8*)(bp0 + 24576);
    bf16x8 b1_1 = *(const bf16x8*)(bp0 + 24576 + 512);
    bf16x8 b1_2 = *(const bf16x8*)(bp0 + 24576 + 1024);
    bf16x8 b1_3 = *(const bf16x8*)(bp0 + 24576 + 1536);

    // ---- one-time A stage: f32 -> bf16, MFMA-fragment order ----
    #pragma unroll
    for (int i = 0; i < 8; ++i) {
        int gf = i * 768 + tid;            // 0..6143 slots (96 frags x 64 lanes)
        int l = gf & 63, f = gf >> 6;      // f = ks*4 + rf
        int ks = f >> 2, rf = f & 3;
        int row = rf * 16 + (l & 15);
        int kb = ks * 32 + (l >> 4) * 8;
        const float* src = desc + (size_t)(blk * BM + row) * DIM + kb;
        float4 v0 = *(const float4*)src;
        float4 v1 = *(const float4*)(src + 4);
        bf16x8 pk;
        pk[0] = (__bf16)v0.x; pk[1] = (__bf16)v0.y; pk[2] = (__bf16)v0.z; pk[3] = (__bf16)v0.w;
        pk[4] = (__bf16)v1.x; pk[5] = (__bf16)v1.y; pk[6] = (__bf16)v1.z; pk[7] = (__bf16)v1.w;
        *(bf16x8*)(aLds + (size_t)f * 512 + l * 8) = pk;
    }
    __syncthreads();

    f32x4 acc[4][4];
    #pragma unroll
    for (int rf = 0; rf < 4; ++rf)
        #pragma unroll
        for (int i = 0; i < 4; ++i) acc[rf][i] = f32x4{0.f, 0.f, 0.f, 0.f};

    const unsigned short* ab0 = aLds + lane * 8;

    // A(0), A(1) into registers
    bf16x8 a0_0 = *(const bf16x8*)(ab0);
    bf16x8 a0_1 = *(const bf16x8*)(ab0 + 512);
    bf16x8 a0_2 = *(const bf16x8*)(ab0 + 1024);
    bf16x8 a0_3 = *(const bf16x8*)(ab0 + 1536);
    bf16x8 a1_0 = *(const bf16x8*)(ab0 + 2048);
    bf16x8 a1_1 = *(const bf16x8*)(ab0 + 2560);
    bf16x8 a1_2 = *(const bf16x8*)(ab0 + 3072);
    bf16x8 a1_3 = *(const bf16x8*)(ab0 + 3584);

    const unsigned short* pa = ab0 + 4096;          // A(2)
    const unsigned short* pb = bp0 + 2 * 24576;     // B(2)

    #pragma unroll 1
    for (int it = 0; it < 12; ++it) {
        // kstep 2it: consume set0 (loaded one full kstep ago)
        MFMA4(a0_0, b0_0, b0_1, b0_2, b0_3, 0)
        MFMA4(a0_1, b0_0, b0_1, b0_2, b0_3, 1)
        MFMA4(a0_2, b0_0, b0_1, b0_2, b0_3, 2)
        MFMA4(a0_3, b0_0, b0_1, b0_2, b0_3, 3)
        if (it < 11) {   // refill set0 with kstep 2it+2
            b0_0 = *(const bf16x8*)(pb);
            b0_1 = *(const bf16x8*)(pb + 512);
            b0_2 = *(const bf16x8*)(pb + 1024);
            b0_3 = *(const bf16x8*)(pb + 1536);
            a0_0 = *(const bf16x8*)(pa);
            a0_1 = *(const bf16x8*)(pa + 512);
            a0_2 = *(const bf16x8*)(pa + 1024);
            a0_3 = *(const bf16x8*)(pa + 1536);
            pb += 24576; pa += 2048;
        }
        __builtin_amdgcn_sched_barrier(0);
        // kstep 2it+1: consume set1
        MFMA4(a1_0, b1_0, b1_1, b1_2, b1_3, 0)
        MFMA4(a1_1, b1_0, b1_1, b1_2, b1_3, 1)
        MFMA4(a1_2, b1_0, b1_1, b1_2, b1_3, 2)
        MFMA4(a1_3, b1_0, b1_1, b1_2, b1_3, 3)
        if (it < 11) {   // refill set1 with kstep 2it+3
            b1_0 = *(const bf16x8*)(pb);
            b1_1 = *(const bf16x8*)(pb + 512);
            b1_2 = *(const bf16x8*)(pb + 1024);
            b1_3 = *(const bf16x8*)(pb + 1536);
            a1_0 = *(const bf16x8*)(pa);
            a1_1 = *(const bf16x8*)(pa + 512);
            a1_2 = *(const bf16x8*)(pa + 1024);
            a1_3 = *(const bf16x8*)(pa + 1536);
            pb += 24576; pa += 2048;
        }
        __builtin_amdgcn_sched_barrier(0);
    }

    // epilogue: per-row sum over this wave's 64 cols of gelu(h+b1)*w2
    int col16 = lane & 15, quart = lane >> 4;
    float b1v[4], w2v[4];
    #pragma unroll
    for (int i = 0; i < 4; ++i) {
        int c = cg * 64 + i * 16 + col16;
        b1v[i] = rb1[c]; w2v[i] = rw2[c];
    }
    #pragma unroll
    for (int rf = 0; rf < 4; ++rf) {
        #pragma unroll
        for (int r = 0; r < 4; ++r) {
            float s = 0.f;
            #pragma unroll
            for (int i = 0; i < 4; ++i)
                s += gelu_f(acc[rf][i][r] + b1v[i]) * w2v[i];
            #pragma unroll
            for (int m = 1; m < 16; m <<= 1) s += __shfl_xor(s, m);
            if (col16 == 0) part[wid * 64 + rf * 16 + quart * 4 + r] = s;
        }
    }
    __syncthreads();
    if (tid < 192) {
        int tt = tid >> 6, row = tid & 63;
        float v = part[(tt * 4 + 0) * 64 + row] + part[(tt * 4 + 1) * 64 + row]
                + part[(tt * 4 + 2) * 64 + row] + part[(tt * 4 + 3) * 64 + row] + rb2[0];
        float p = 1.f / (1.f + __expf(-v));
        dprob[(size_t)tt * NUM_EDGES + blk * BM + row] = p;
    }
}

// Kzero: zero raw accumulators e1..e3
__global__ void kzero(float* __restrict__ ws) {
    int i = blockIdx.x * 256 + threadIdx.x;
    if (i < 3 * NUM_ENT) ws[WS_E + NUM_ENT + i] = 0.f;
}

// K9: scatter step t: e_{t+1}[obj] += norm(e_t)[sub] * dprob[t][e]
__global__ void k9_scatter(const int* __restrict__ kb, const int* __restrict__ topics,
                           float* __restrict__ ws, int t) {
    int e = blockIdx.x * 256 + threadIdx.x;
    if (e >= NUM_EDGES) return;
    int sub = kb[2 * e], obj = kb[2 * e + 1];
    float g;
    if (t == 0) {
        g = (sub == topics[0] || sub == topics[1] || sub == topics[2] || sub == topics[3]) ? 1.f : 0.f;
    } else {
        float v = ws[WS_E + (size_t)t * NUM_ENT + sub];
        g = v / fmaxf(v, 1.f);
    }
    float p = g * ws[WS_DPROB + (size_t)t * NUM_EDGES + e];
    if (p != 0.f) atomicAdd(&ws[WS_E + (size_t)(t + 1) * NUM_ENT + obj], p);
}

// Kout: out[i] = sum_t hop_attn[t] * norm(e_{t+1})[i]
__global__ void kout(const float* __restrict__ ws, float* __restrict__ out) {
    int i = blockIdx.x * 256 + threadIdx.x;
    if (i >= NUM_ENT) return;
    float v1 = ws[WS_E + 1 * NUM_ENT + i]; v1 /= fmaxf(v1, 1.f);
    float v2 = ws[WS_E + 2 * NUM_ENT + i]; v2 /= fmaxf(v2, 1.f);
    float v3 = ws[WS_E + 3 * NUM_ENT + i]; v3 /= fmaxf(v3, 1.f);
    out[i] = ws[WS_HA + 0] * v1 + ws[WS_HA + 1] * v2 + ws[WS_HA + 2] * v3;
}

extern "C" void kernel_launch(void* const* d_in, const int* in_sizes, int n_in,
                              void* d_out, int out_size, void* d_ws, size_t ws_size,
                              hipStream_t stream) {
    const float* q_emb   = (const float*)d_in[0];
    const float* qwh     = (const float*)d_in[1];
    const float* desc    = (const float*)d_in[2];
    const float* sw1     = (const float*)d_in[3];
    const float* sb1     = (const float*)d_in[4];
    const float* sw2     = (const float*)d_in[5];
    const float* sb2     = (const float*)d_in[6];
    const float* rw1     = (const float*)d_in[7];
    const float* rb1     = (const float*)d_in[8];
    const float* rw2     = (const float*)d_in[9];
    const float* rb2     = (const float*)d_in[10];
    const float* hw1     = (const float*)d_in[11];
    const float* hb1     = (const float*)d_in[12];
    const float* hw2     = (const float*)d_in[13];
    const float* hb2     = (const float*)d_in[14];
    const int*   kb      = (const int*)d_in[15];
    const int*   topics  = (const int*)d_in[16];
    float* ws  = (float*)d_ws;
    float* out = (float*)d_out;

    int nblk7 = NUM_EDGES / BM;   // 3125, exact

    kzero<<<(3 * NUM_ENT + 255) / 256, 256, 0, stream>>>(ws);
    k1a<<<64, 256, 0, stream>>>(q_emb, sw1, hw1, ws);
    k1b<<<10, 256, 0, stream>>>(sb1, hb1, ws);
    k2a<<<48, 256, 0, stream>>>(sw2, ws);
    k2b<<<9, 256, 0, stream>>>(sb2, ws);
    k345<<<1, 1024, 0, stream>>>(qwh, hw2, hb2, ws);
    k6_bmat<<<288, 256, 0, stream>>>(rw1, ws);
    k7_gemm<<<nblk7, 768, 101376, stream>>>(desc, rb1, rw2, rb2, ws);
    for (int t = 0; t < 3; ++t)
        k9_scatter<<<(NUM_EDGES + 255) / 256, 256, 0, stream>>>(kb, topics, ws, t);
    kout<<<(NUM_ENT + 255) / 256, 256, 0, stream>>>(ws, out);
}